// Round 11
// baseline (209.423 us; speedup 1.0000x reference)
//
#include <hip/hip_runtime.h>
#include <hip/hip_bf16.h>

// L=256, B=32, H=8, d_head=64, m=256, feature dim 2m=512, D_MODEL=512
#define L_SEQ 256
#define B_SZ  32
#define NH    8
#define DH    64
#define DM    512
#define FD    512
#define PM    256
#define ROWS  8192
#define QKVN  2048

typedef __bf16 bf16x8 __attribute__((ext_vector_type(8)));
typedef __bf16 bf16x4 __attribute__((ext_vector_type(4)));
typedef float f32x4 __attribute__((ext_vector_type(4)));
#define MFMA16(a, b, c) __builtin_amdgcn_mfma_f32_16x16x32_bf16((a), (b), (c), 0, 0, 0)

static __device__ __forceinline__ void stmix(void* p, long i, float v, int f32) {
  if (f32) ((float*)p)[i] = v;
  else     ((__bf16*)p)[i] = (__bf16)v;
}

static __device__ __forceinline__ void gload_lds16(const __bf16* g, __bf16* lds) {
  __builtin_amdgcn_global_load_lds(
      (const __attribute__((address_space(1))) void*)g,
      (__attribute__((address_space(3))) void*)lds, 16, 0, 0);
}

// ---------------------------------------------------------------------------
// P0: prep — probe + h-cvt + 3 transposes + tiny cvts + projB/wotB packs.
// projB chunk (c,kk), lane=q*16+m, elem e: projT[p=c*16+m][d=kk*32+q*8+e].
// wotB  chunk (cb,kk), lane=q*16+m, elem e: wot[n=cb*16+m][k=kk*32+q*8+e]
//   (packed from the same LDS transpose tile, validated projB pattern).
// ---------------------------------------------------------------------------
#define PREP_HB   2048
#define PREP_WT   256
#define PREP_WOT  64
#define PREP_PJ   4
#define PREP_TINY 1
#define PREP_BLOCKS (PREP_HB + PREP_WT + PREP_WOT + PREP_PJ + PREP_TINY)

__global__ __launch_bounds__(256) void prep(
    const void* __restrict__ h, const void* __restrict__ wqkv,
    const void* __restrict__ wo, const void* __restrict__ proj,
    const void* __restrict__ pi0, const void* __restrict__ pi1,
    const void* __restrict__ gam, const void* __restrict__ bet,
    int* __restrict__ flag, __bf16* __restrict__ hb, __bf16* __restrict__ wt,
    __bf16* __restrict__ wot, __bf16* __restrict__ projT,
    __bf16* __restrict__ pi0b, __bf16* __restrict__ pi1b,
    __bf16* __restrict__ gamb, __bf16* __restrict__ betb,
    __bf16* __restrict__ projB, __bf16* __restrict__ wotB) {
  __shared__ float T[64][69];
  __shared__ int red[256];
  const int tid = threadIdx.x;
  int cnt = 0;
  {
    const unsigned short* hbits = (const unsigned short*)h;
    for (int i = 0; i < 16; ++i) {
      const unsigned short u = hbits[tid * 16 + i];
      if (((u >> 7) & 0xFF) >= 0xA0) ++cnt;
    }
  }
  red[tid] = cnt; __syncthreads();
  for (int s = 128; s > 0; s >>= 1) { if (tid < s) red[tid] += red[tid + s]; __syncthreads(); }
  const int f32 = (red[0] >= 64) ? 1 : 0;
  __syncthreads();

  const int blk = blockIdx.x;
  if (blk < PREP_HB) {
    const int i = blk * 256 + tid;
    if (f32) {
      const f32x4* s = (const f32x4*)h;
      const f32x4 a = s[i * 2], b = s[i * 2 + 1];
      bf16x8 t;
      t[0] = (__bf16)a[0]; t[1] = (__bf16)a[1]; t[2] = (__bf16)a[2]; t[3] = (__bf16)a[3];
      t[4] = (__bf16)b[0]; t[5] = (__bf16)b[1]; t[6] = (__bf16)b[2]; t[7] = (__bf16)b[3];
      *reinterpret_cast<bf16x8*>(hb + (long)i * 8) = t;
    } else {
      *reinterpret_cast<bf16x8*>(hb + (long)i * 8) = ((const bf16x8*)h)[i];
    }
    return;
  }
  const void* src; __bf16* dst; int M, N, n0, m0;
  int pjx = -1, wox = -1;
  if (blk < PREP_HB + PREP_WT) {
    const int x = blk - PREP_HB;
    src = wqkv; dst = wt; M = 512; N = 2048; n0 = (x & 31) * 64; m0 = (x >> 5) * 64;
  } else if (blk < PREP_HB + PREP_WT + PREP_WOT) {
    const int x = blk - PREP_HB - PREP_WT;
    src = wo; dst = wot; M = 512; N = 512; n0 = (x & 7) * 64; m0 = (x >> 3) * 64;
    wox = x;
  } else if (blk < PREP_HB + PREP_WT + PREP_WOT + PREP_PJ) {
    const int x = blk - PREP_HB - PREP_WT - PREP_WOT;
    src = proj; dst = projT; M = 64; N = 256; n0 = x * 64; m0 = 0;
    pjx = x;
  } else {
    if (tid == 0) flag[0] = f32;
    if (f32) {
      const float* s0 = (const float*)pi0; const float* s1 = (const float*)pi1;
      const float* s2 = (const float*)gam; const float* s3 = (const float*)bet;
      for (int i = tid; i < NH * 256; i += 256) { pi0b[i] = (__bf16)s0[i]; pi1b[i] = (__bf16)s1[i]; }
      for (int i = tid; i < DM; i += 256)      { gamb[i] = (__bf16)s2[i]; betb[i] = (__bf16)s3[i]; }
    } else {
      const __bf16* s0 = (const __bf16*)pi0; const __bf16* s1 = (const __bf16*)pi1;
      const __bf16* s2 = (const __bf16*)gam; const __bf16* s3 = (const __bf16*)bet;
      for (int i = tid; i < NH * 256; i += 256) { pi0b[i] = s0[i]; pi1b[i] = s1[i]; }
      for (int i = tid; i < DM; i += 256)      { gamb[i] = s2[i]; betb[i] = s3[i]; }
    }
    return;
  }
  if (f32) {
    const float* s = (const float*)src;
#pragma unroll
    for (int rep = 0; rep < 16; ++rep) {
      const int i = rep * 4 + (tid >> 6), j = tid & 63;
      T[i][j] = s[(long)(m0 + i) * N + n0 + j];
    }
  } else {
    const __bf16* s = (const __bf16*)src;
#pragma unroll
    for (int rep = 0; rep < 16; ++rep) {
      const int i = rep * 4 + (tid >> 6), j = tid & 63;
      T[i][j] = (float)s[(long)(m0 + i) * N + n0 + j];
    }
  }
  __syncthreads();
#pragma unroll
  for (int rep = 0; rep < 16; ++rep) {
    const int i = rep * 4 + (tid >> 6), j = tid & 63;
    dst[(long)(n0 + i) * M + m0 + j] = (__bf16)T[j][i];
  }
  if (pjx >= 0) {
    // fragment-native pack. T[d][p-n0] (rows = d, cols = feature):
    const int lane = tid & 63, sub = tid >> 6;
    const int mm = lane & 15, qq = lane >> 4;
#pragma unroll
    for (int kk2 = 0; kk2 < 2; ++kk2) {
      bf16x8 v;
#pragma unroll
      for (int e = 0; e < 8; ++e) v[e] = (__bf16)T[kk2 * 32 + qq * 8 + e][sub * 16 + mm];
      *reinterpret_cast<bf16x8*>(projB + ((pjx * 4 + sub) * 2 + kk2) * 512 + lane * 8) = v;
    }
  }
  if (wox >= 0) {
    // wotB pack: T[i][j] = wo[m0+i][n0+j]; chunk (cb0+sub, kk0+kk2), elem e =
    // wot[n=cb*16+mm][k=kk*32+qq*8+e] = wo[k][n] = T[kk2*32+qq*8+e][sub*16+mm].
    const int lane = tid & 63, sub = tid >> 6;
    const int mm = lane & 15, qq = lane >> 4;
    const int cb0 = n0 >> 4, kk0 = m0 >> 5;
#pragma unroll
    for (int kk2 = 0; kk2 < 2; ++kk2) {
      bf16x8 v;
#pragma unroll
      for (int e = 0; e < 8; ++e) v[e] = (__bf16)T[kk2 * 32 + qq * 8 + e][sub * 16 + mm];
      *reinterpret_cast<bf16x8*>(wotB + (((cb0 + sub) * 16) + kk0 + kk2) * 512 + lane * 8) = v;
    }
  }
}

// ---------------------------------------------------------------------------
// K1: qkv = hb @ w_qkv, 128x128 tile, BK=64, per-wave 64x64 (validated r13).
// ---------------------------------------------------------------------------
__global__ __launch_bounds__(256) void gemm_h_wqkv(const __bf16* __restrict__ A,
                                                   const __bf16* __restrict__ Bt,
                                                   __bf16* __restrict__ C) {
  __shared__ __bf16 At[128][72];
  __shared__ __bf16 Bts[128][72];
  const int n0 = blockIdx.x * 128, m0 = blockIdx.y * 128;
  const int tid = threadIdx.x, lane = tid & 63, wv = tid >> 6;
  const int m = lane & 15, q = lane >> 4;
  const int wr = (wv >> 1) * 64, wc = (wv & 1) * 64;
  const int r = tid >> 1, c0 = (tid & 1) * 32;
  const __bf16* ap = A + (long)(m0 + r) * DM + c0;
  const __bf16* bp = Bt + (long)(n0 + r) * DM + c0;
  f32x4 acc[4][4];
#pragma unroll
  for (int i = 0; i < 4; ++i)
#pragma unroll
    for (int j = 0; j < 4; ++j) acc[i][j] = f32x4{0.f, 0.f, 0.f, 0.f};

  bf16x8 ar[4], br[4];
#pragma unroll
  for (int j = 0; j < 4; ++j) {
    ar[j] = *reinterpret_cast<const bf16x8*>(ap + j * 8);
    br[j] = *reinterpret_cast<const bf16x8*>(bp + j * 8);
  }
  for (int k0 = 0; k0 < DM; k0 += 64) {
    __syncthreads();
#pragma unroll
    for (int j = 0; j < 4; ++j) {
      *reinterpret_cast<bf16x8*>(&At[r][c0 + j * 8]) = ar[j];
      *reinterpret_cast<bf16x8*>(&Bts[r][c0 + j * 8]) = br[j];
    }
    if (k0 + 64 < DM) {
#pragma unroll
      for (int j = 0; j < 4; ++j) {
        ar[j] = *reinterpret_cast<const bf16x8*>(ap + k0 + 64 + j * 8);
        br[j] = *reinterpret_cast<const bf16x8*>(bp + k0 + 64 + j * 8);
      }
    }
    __syncthreads();
#pragma unroll
    for (int kk = 0; kk < 2; ++kk) {
      bf16x8 af[4], bfv[4];
#pragma unroll
      for (int i = 0; i < 4; ++i) {
        af[i]  = *reinterpret_cast<const bf16x8*>(&At[wr + i * 16 + m][kk * 32 + q * 8]);
        bfv[i] = *reinterpret_cast<const bf16x8*>(&Bts[wc + i * 16 + m][kk * 32 + q * 8]);
      }
#pragma unroll
      for (int ai = 0; ai < 4; ++ai)
#pragma unroll
        for (int bi = 0; bi < 4; ++bi)
          acc[ai][bi] = MFMA16(af[ai], bfv[bi], acc[ai][bi]);
    }
  }
#pragma unroll
  for (int ai = 0; ai < 4; ++ai)
#pragma unroll
    for (int r2 = 0; r2 < 4; ++r2)
#pragma unroll
      for (int bi = 0; bi < 4; ++bi)
        C[(long)(m0 + wr + ai * 16 + q * 4 + r2) * QKVN + n0 + wc + bi * 16 + m] =
            (__bf16)acc[ai][bi][r2];
}

// ---------------------------------------------------------------------------
// K2: kf-features + FUSED V-pack (validated round 15).
// ---------------------------------------------------------------------------
__global__ __launch_bounds__(256) void features_mfma(const __bf16* __restrict__ qkv,
                                                     const __bf16* __restrict__ projB,
                                                     const __bf16* __restrict__ pi0,
                                                     const __bf16* __restrict__ pi1,
                                                     __bf16* __restrict__ kf,
                                                     __bf16* __restrict__ vt) {
  const int st = blockIdx.x;
  const int l0 = st * 64;
  const int bh = blockIdx.y;
  const int h = bh & 7, b = bh >> 3;
  const int tid = threadIdx.x, lane = tid & 63, wv = tid >> 6;
  const int m = lane & 15, q = lane >> 4;
  __shared__ __bf16 As[2][64][72];   // k1 / k2 tiles: 64 l-rows x 64 d
  __shared__ __bf16 VT[64][72];      // V transpose [d][s]

  {
    const int r = tid >> 2, c0 = (tid & 3) * 16;
    const __bf16* ap = qkv + (long)((l0 + r) * B_SZ + b) * QKVN + h * 256 + 64 + c0;
#pragma unroll
    for (int t2 = 0; t2 < 2; ++t2) {
      *reinterpret_cast<bf16x8*>(&As[t2][r][c0]) =
          *reinterpret_cast<const bf16x8*>(ap + t2 * 64);
      *reinterpret_cast<bf16x8*>(&As[t2][r][c0 + 8]) =
          *reinterpret_cast<const bf16x8*>(ap + t2 * 64 + 8);
    }
    // V slice -> transpose into VT
    const __bf16* vp = ap + 128;       // offset 192 = 64 + 128
#pragma unroll
    for (int j = 0; j < 16; ++j) VT[c0 + j][r] = vp[j];
  }
  const int l = l0 + wv * 16 + m;          // this thread's sequence row
  const float p0w = (float)pi0[h * 256 + l];
  const float p1w = (float)pi1[h * 256 + l];
  const float SQ = 0.35355339f;            // 64^-0.25
  const float SK2 = 0.24748737f;           // 0.7 * 64^-0.25
  __syncthreads();

  // V-pack store (fragment-native chunks), overlaps following VALU work
  {
    const int c2 = tid >> 6;
    const int d = c2 * 16 + m;
#pragma unroll
    for (int kk = 0; kk < 2; ++kk) {
      const bf16x8 v = *reinterpret_cast<const bf16x8*>(&VT[d][kk * 32 + q * 8]);
      *reinterpret_cast<bf16x8*>(vt + (((long)bh * 8 + st * 2 + kk) * 4 + c2) * 512 + lane * 8) = v;
    }
  }

  f32x4 acc1[16], acc2[16];
#pragma unroll
  for (int c = 0; c < 16; ++c) {
    acc1[c] = f32x4{0.f, 0.f, 0.f, 0.f};
    acc2[c] = f32x4{0.f, 0.f, 0.f, 0.f};
  }
#pragma unroll
  for (int kk = 0; kk < 2; ++kk) {
    const bf16x8 x1 = *reinterpret_cast<const bf16x8*>(&As[0][wv * 16 + m][kk * 32 + q * 8]);
    const bf16x8 x2 = *reinterpret_cast<const bf16x8*>(&As[1][wv * 16 + m][kk * 32 + q * 8]);
#pragma unroll
    for (int c = 0; c < 16; ++c) {
      const bf16x8 wf =
          *reinterpret_cast<const bf16x8*>(projB + (c * 2 + kk) * 512 + lane * 8);
      acc1[c] = MFMA16(wf, x1, acc1[c]);   // acc[c][r] = [l=wv*16+m][p=c*16+q*4+r]
      acc2[c] = MFMA16(wf, x2, acc2[c]);
    }
  }
  float mx1 = 0.f, mx2 = 0.f;
#pragma unroll
  for (int c = 0; c < 16; ++c)
#pragma unroll
    for (int r = 0; r < 4; ++r) {
      mx1 = fmaxf(mx1, fabsf(acc1[c][r] * SQ));
      mx2 = fmaxf(mx2, fabsf(acc2[c][r] * SK2));
    }
  mx1 = fmaxf(mx1, __shfl_xor(mx1, 16)); mx1 = fmaxf(mx1, __shfl_xor(mx1, 32));
  mx2 = fmaxf(mx2, __shfl_xor(mx2, 16)); mx2 = fmaxf(mx2, __shfl_xor(mx2, 32));
  const float C21 = __expf(-2.f * mx1);
  const float C22 = __expf(-2.f * mx2);
  float sm1 = 0.f, sm2 = 0.f;
#pragma unroll
  for (int c = 0; c < 16; ++c)
#pragma unroll
    for (int r = 0; r < 4; ++r) {
      const float e11 = __expf(acc1[c][r] * SQ - mx1);
      const float e12 = __expf(acc2[c][r] * SK2 - mx2);
      sm1 += e11 + C21 * __builtin_amdgcn_rcpf(e11);
      sm2 += e12 + C22 * __builtin_amdgcn_rcpf(e12);
      acc1[c][r] = e11;
      acc2[c][r] = e12;
    }
  sm1 += __shfl_xor(sm1, 16); sm1 += __shfl_xor(sm1, 32);
  sm2 += __shfl_xor(sm2, 16); sm2 += __shfl_xor(sm2, 32);
  const float w1 = p0w * __builtin_amdgcn_rcpf(sm1);
  const float w2 = p1w * __builtin_amdgcn_rcpf(sm2);
  const float K1 = C21 * w1, K2 = C22 * w2;
  // fragment-native store: chunk [lt = l>>4][c], lane offset = lane*8
  __bf16* op = kf + (((long)bh * 16 + (l >> 4)) * 16) * 512 + lane * 8;
#pragma unroll
  for (int c = 0; c < 16; ++c) {
    bf16x8 v;
#pragma unroll
    for (int r = 0; r < 4; ++r) {
      v[r]     = (__bf16)(w1 * acc1[c][r] + w2 * acc2[c][r]);
      v[4 + r] = (__bf16)(K1 * __builtin_amdgcn_rcpf(acc1[c][r]) +
                          K2 * __builtin_amdgcn_rcpf(acc2[c][r]));
    }
    *reinterpret_cast<bf16x8*>(op + c * 512) = v;
  }
}

// ---------------------------------------------------------------------------
// K3: flash (validated round 18): kf step-tile staged into LDS via
// global_load_lds (contiguous 64KB in lane order), 2 barriers/step,
// longest-first dispatch, XCD locality.
// ---------------------------------------------------------------------------
__global__ __launch_bounds__(256, 2) void flash_mfma(const __bf16* __restrict__ qkv,
                                                     const __bf16* __restrict__ projB,
                                                     const __bf16* __restrict__ kf,
                                                     const __bf16* __restrict__ vt,
                                                     __bf16* __restrict__ att) {
  const int id = blockIdx.x;
  const int bh = id & 255;
  const int t  = 3 - (id >> 8);          // longest-first dispatch order
  const int h = bh & 7, b = bh >> 3;
  const int tid = threadIdx.x, lane = tid & 63, wv = tid >> 6;
  const int m = lane & 15, q = lane >> 4;
  __shared__ __bf16 Kst[4 * 16 * 512];   // 64 KB staged kf step-tile
  __shared__ __bf16 Pt[64][72];          // wave-private rows

  // ---------------- feature phase: qT[16] in-register ----------------
  const float SQ = 0.35355339f;          // 64^-0.25
  f32x4 acc[16];
#pragma unroll
  for (int c = 0; c < 16; ++c) acc[c] = f32x4{0.f, 0.f, 0.f, 0.f};
  const __bf16* xb = qkv + (long)((t * 64 + wv * 16 + m) * B_SZ + b) * QKVN + h * 256;
#pragma unroll
  for (int kk = 0; kk < 2; ++kk) {
    const bf16x8 xf = *reinterpret_cast<const bf16x8*>(xb + kk * 32 + q * 8);
#pragma unroll
    for (int c = 0; c < 16; ++c) {
      const bf16x8 wf =
          *reinterpret_cast<const bf16x8*>(projB + (c * 2 + kk) * 512 + lane * 8);
      acc[c] = MFMA16(wf, xf, acc[c]);   // acc[c][r] = qf-pre[l=wv*16+m][p=c*16+q*4+r]
    }
  }
  float mx = 0.f;
#pragma unroll
  for (int c = 0; c < 16; ++c)
#pragma unroll
    for (int r = 0; r < 4; ++r) mx = fmaxf(mx, fabsf(acc[c][r] * SQ));
  mx = fmaxf(mx, __shfl_xor(mx, 16));
  mx = fmaxf(mx, __shfl_xor(mx, 32));
  const float C2 = __expf(-2.f * mx);
  float sm = 0.f;
#pragma unroll
  for (int c = 0; c < 16; ++c)
#pragma unroll
    for (int r = 0; r < 4; ++r) {
      const float e1 = __expf(acc[c][r] * SQ - mx);
      sm += e1 + C2 * __builtin_amdgcn_rcpf(e1);
      acc[c][r] = e1;
    }
  sm += __shfl_xor(sm, 16);
  sm += __shfl_xor(sm, 32);
  const float inv = __builtin_amdgcn_rcpf(sm);
  const float K2 = C2 * inv;
  bf16x8 qT[16];                         // A-frags, k = q*8 + (r + 4*neg)
#pragma unroll
  for (int c = 0; c < 16; ++c) {
    bf16x8 v;
#pragma unroll
    for (int r = 0; r < 4; ++r) {
      v[r]     = (__bf16)(acc[c][r] * inv);
      v[4 + r] = (__bf16)(K2 * __builtin_amdgcn_rcpf(acc[c][r]));
    }
    qT[c] = v;
  }

  // ---------------- main loop: LDS-staged kf, 2 barriers/step ----------------
  f32x4 o[4];
#pragma unroll
  for (int i = 0; i < 4; ++i) o[i] = f32x4{0.f, 0.f, 0.f, 0.f};
  float den[4] = {0.f, 0.f, 0.f, 0.f};

  const __bf16* kf_bh = kf + (long)bh * (16 * 16 * 512);
  const __bf16* vtb = vt + (long)bh * (8 * 4 * 512) + lane * 8;

  for (int st = 0; st <= t; ++st) {
    __syncthreads();                     // previous step's reads done
    {
      const __bf16* gsrc =
          kf_bh + ((long)(st * 4) * 16 + wv * 16) * 512 + lane * 8;
      __bf16* ldst = Kst + (wv * 16) * 512;
#pragma unroll
      for (int j = 0; j < 16; ++j)
        gload_lds16(gsrc + j * 512, ldst + j * 512);
    }
    // V fragments for this step (register-direct, L1-shared across waves)
    bf16x8 vf[8];
#pragma unroll
    for (int kk = 0; kk < 2; ++kk)
#pragma unroll
      for (int c = 0; c < 4; ++c)
        vf[kk * 4 + c] =
            *reinterpret_cast<const bf16x8*>(vtb + (((long)st * 2 + kk) * 4 + c) * 512);
    __syncthreads();                     // staging visible (vmcnt drained)

    f32x4 s[4];
#pragma unroll
    for (int i = 0; i < 4; ++i) s[i] = f32x4{0.f, 0.f, 0.f, 0.f};
#pragma unroll
    for (int g = 0; g < 16; ++g) {
      const __bf16* kp = Kst + (long)g * 512 + lane * 8;
      const bf16x8 kb0 = *reinterpret_cast<const bf16x8*>(kp);
      const bf16x8 kb1 = *reinterpret_cast<const bf16x8*>(kp + 16 * 512);
      const bf16x8 kb2 = *reinterpret_cast<const bf16x8*>(kp + 32 * 512);
      const bf16x8 kb3 = *reinterpret_cast<const bf16x8*>(kp + 48 * 512);
      s[0] = MFMA16(qT[g], kb0, s[0]);
      s[1] = MFMA16(qT[g], kb1, s[1]);
      s[2] = MFMA16(qT[g], kb2, s[2]);
      s[3] = MFMA16(qT[g], kb3, s[3]);
    }
    const bool last = (st == t);
#pragma unroll
    for (int c = 0; c < 4; ++c)
#pragma unroll
      for (int r = 0; r < 4; ++r) {
        const int row = wv * 16 + q * 4 + r, col = c * 16 + m;
        const float v = (last && col > row) ? 0.f : s[c][r];
        den[r] += v;
        Pt[row][col] = (__bf16)v;
      }
#pragma unroll
    for (int kk = 0; kk < 2; ++kk) {
      const bf16x8 pf = *reinterpret_cast<const bf16x8*>(&Pt[wv * 16 + m][kk * 32 + q * 8]);
#pragma unroll
      for (int c = 0; c < 4; ++c)
        o[c] = MFMA16(pf, vf[kk * 4 + c], o[c]);
    }
  }
#pragma unroll
  for (int r = 0; r < 4; ++r) {
    float d = den[r];
    d += __shfl_xor(d, 1); d += __shfl_xor(d, 2);
    d += __shfl_xor(d, 4); d += __shfl_xor(d, 8);
    const float invd = 0.125f / (d + 1e-5f);           // SCALE=64^-0.5, EPS
    const int row = t * 64 + wv * 16 + q * 4 + r;
#pragma unroll
    for (int c = 0; c < 4; ++c)
      att[((long)(row * B_SZ + b)) * DM + h * DH + c * 16 + m] = (__bf16)(o[c][r] * invd);
  }
}

// ---------------------------------------------------------------------------
// K4+K5 FUSED (round 19): out = LN(hb + att @ w_o). Block owns 32 FULL rows
// (all 512 cols) so the LN row-reduce happens in-kernel — eliminates the
// 32 MB xrow roundtrip and one launch. 512 threads = 8 waves: wave wv does
// rowblock rb=wv>>2, colrange wc=(wv&3)*128 (acc = 8 f32x4). B-operand =
// fragment-native wotB chunks (coalesced 1KB, L2-hot). A staged in LDS
// (stride-520 = validated bank class). Epilogue: residual + shfl row-stats +
// LDS cross-wave partials + gamma/beta + dtype store. Numerics identical to
// the old xrow path.
// ---------------------------------------------------------------------------
__global__ __launch_bounds__(512) void gemm_wo_ln(const __bf16* __restrict__ att,
                                                  const __bf16* __restrict__ wotB,
                                                  const __bf16* __restrict__ hb,
                                                  const __bf16* __restrict__ gamma,
                                                  const __bf16* __restrict__ beta,
                                                  const int* __restrict__ flag,
                                                  void* __restrict__ out) {
  const int f32 = flag[0];
  const int bm = blockIdx.x;             // rows [bm*32, bm*32+32)
  const int tid = threadIdx.x, lane = tid & 63, wv = tid >> 6;
  const int m = lane & 15, q = lane >> 4;
  const int rb = wv >> 2;                // rowblock 0/1
  const int wc = (wv & 3) * 128;         // col range
  __shared__ __bf16 As[32][520];
  __shared__ float RedS[32][4], RedS2[32][4];

  // stage att rows: per (j, wave) exactly one full row, fully coalesced
#pragma unroll
  for (int j = 0; j < 4; ++j) {
    const int ci = j * 512 + tid;
    const int r = ci >> 6, c = (ci & 63) * 8;
    *reinterpret_cast<bf16x8*>(&As[r][c]) =
        *reinterpret_cast<const bf16x8*>(att + ((long)(bm * 32 + r)) * DM + c);
  }
  __syncthreads();

  f32x4 acc[8];
#pragma unroll
  for (int i = 0; i < 8; ++i) acc[i] = f32x4{0.f, 0.f, 0.f, 0.f};
#pragma unroll
  for (int kk = 0; kk < 16; ++kk) {
    const bf16x8 af = *reinterpret_cast<const bf16x8*>(&As[rb * 16 + m][kk * 32 + q * 8]);
#pragma unroll
    for (int cbl = 0; cbl < 8; ++cbl) {
      const bf16x8 bf = *reinterpret_cast<const bf16x8*>(
          wotB + ((((wv & 3) * 8 + cbl) * 16) + kk) * 512 + lane * 8);
      acc[cbl] = MFMA16(af, bf, acc[cbl]);
    }
  }

  // residual + per-row stats
  float s[4] = {0.f, 0.f, 0.f, 0.f}, s2[4] = {0.f, 0.f, 0.f, 0.f};
#pragma unroll
  for (int cbl = 0; cbl < 8; ++cbl)
#pragma unroll
    for (int r = 0; r < 4; ++r) {
      const long row = (long)bm * 32 + rb * 16 + q * 4 + r;
      const int col = wc + cbl * 16 + m;
      const float x = acc[cbl][r] + (float)hb[row * DM + col];
      acc[cbl][r] = x;
      s[r] += x;
      s2[r] += x * x;
    }
#pragma unroll
  for (int msk = 1; msk < 16; msk <<= 1)
#pragma unroll
    for (int r = 0; r < 4; ++r) {
      s[r] += __shfl_xor(s[r], msk);
      s2[r] += __shfl_xor(s2[r], msk);
    }
  if (m == 0) {
#pragma unroll
    for (int r = 0; r < 4; ++r) {
      RedS[rb * 16 + q * 4 + r][wv & 3] = s[r];
      RedS2[rb * 16 + q * 4 + r][wv & 3] = s2[r];
    }
  }
  __syncthreads();

  float gam[8], bet[8];
#pragma unroll
  for (int cbl = 0; cbl < 8; ++cbl) {
    gam[cbl] = (float)gamma[wc + cbl * 16 + m];
    bet[cbl] = (float)beta[wc + cbl * 16 + m];
  }
#pragma unroll
  for (int r = 0; r < 4; ++r) {
    const int rl = rb * 16 + q * 4 + r;
    const float fs = RedS[rl][0] + RedS[rl][1] + RedS[rl][2] + RedS[rl][3];
    const float fs2 = RedS2[rl][0] + RedS2[rl][1] + RedS2[rl][2] + RedS2[rl][3];
    const float mu = fs * (1.f / 512.f);
    const float var = fs2 * (1.f / 512.f) - mu * mu;
    const float rstd = rsqrtf(var + 1e-5f);
    const long row = (long)bm * 32 + rl;
#pragma unroll
    for (int cbl = 0; cbl < 8; ++cbl) {
      const int col = wc + cbl * 16 + m;
      stmix(out, row * DM + col, (acc[cbl][r] - mu) * rstd * gam[cbl] + bet[cbl], f32);
    }
  }
}

// ---------------------------------------------------------------------------
extern "C" void kernel_launch(void* const* d_in, const int* in_sizes, int n_in,
                              void* d_out, int out_size, void* d_ws, size_t ws_size,
                              hipStream_t stream) {
  (void)in_sizes; (void)n_in; (void)out_size; (void)ws_size;
  char* ws = (char*)d_ws;
  __bf16* qkv   = (__bf16*)ws;
  int*    flag  = (int*)(ws + 33554432);
  __bf16* wt    = (__bf16*)(ws + 33554688);
  __bf16* wot   = (__bf16*)(ws + 35651840);
  __bf16* att   = (__bf16*)(ws + 36176128);
  __bf16* vt    = (__bf16*)(ws + 44564736);
  __bf16* hb    = (__bf16*)(ws + 52953344);
  __bf16* projT = (__bf16*)(ws + 61341952);
  __bf16* pi0b  = (__bf16*)(ws + 61374720);
  __bf16* pi1b  = (__bf16*)(ws + 61378816);
  __bf16* gamb  = (__bf16*)(ws + 61382912);
  __bf16* betb  = (__bf16*)(ws + 61383936);
  __bf16* projB = (__bf16*)(ws + 78163968);  // 32 KB fragment-native proj
  __bf16* wotB  = (__bf16*)(ws + 78196736);  // 512 KB fragment-native w_o^T
  __bf16* kf    = (__bf16*)(ws + 128493824);

  prep<<<PREP_BLOCKS, 256, 0, stream>>>(d_in[0], d_in[1], d_in[2], d_in[7],
                                        d_in[5], d_in[6], d_in[3], d_in[4],
                                        flag, hb, wt, wot, projT,
                                        pi0b, pi1b, gamb, betb, projB, wotB);
  gemm_h_wqkv<<<dim3(16, 64), 256, 0, stream>>>(hb, wt, qkv);
  features_mfma<<<dim3(4, 256), 256, 0, stream>>>(qkv, projB, pi0b, pi1b, kf, vt);
  flash_mfma<<<dim3(1024), 256, 0, stream>>>(qkv, projB, kf, vt, att);
  gemm_wo_ln<<<dim3(256), 512, 0, stream>>>(att, wotB, hb, gamb, betb, flag, d_out);
}

// Round 12
// 197.206 us; speedup vs baseline: 1.0619x; 1.0619x over previous
//
#include <hip/hip_runtime.h>
#include <hip/hip_bf16.h>

// L=256, B=32, H=8, d_head=64, m=256, feature dim 2m=512, D_MODEL=512
#define L_SEQ 256
#define B_SZ  32
#define NH    8
#define DH    64
#define DM    512
#define FD    512
#define PM    256
#define ROWS  8192
#define QKVN  2048

typedef __bf16 bf16x8 __attribute__((ext_vector_type(8)));
typedef __bf16 bf16x4 __attribute__((ext_vector_type(4)));
typedef float f32x4 __attribute__((ext_vector_type(4)));
#define MFMA16(a, b, c) __builtin_amdgcn_mfma_f32_16x16x32_bf16((a), (b), (c), 0, 0, 0)

static __device__ __forceinline__ void stmix(void* p, long i, float v, int f32) {
  if (f32) ((float*)p)[i] = v;
  else     ((__bf16*)p)[i] = (__bf16)v;
}

static __device__ __forceinline__ void gload_lds16(const __bf16* g, __bf16* lds) {
  __builtin_amdgcn_global_load_lds(
      (const __attribute__((address_space(1))) void*)g,
      (__attribute__((address_space(3))) void*)lds, 16, 0, 0);
}

// ---------------------------------------------------------------------------
// P0: prep — probe + h-cvt + 3 transposes + tiny cvts + projB/wotB packs.
// Round 20: probe = wave shfl-reduce + 1 barrier (was 8-barrier LDS tree).
// ---------------------------------------------------------------------------
#define PREP_HB   2048
#define PREP_WT   256
#define PREP_WOT  64
#define PREP_PJ   4
#define PREP_TINY 1
#define PREP_BLOCKS (PREP_HB + PREP_WT + PREP_WOT + PREP_PJ + PREP_TINY)

__global__ __launch_bounds__(256) void prep(
    const void* __restrict__ h, const void* __restrict__ wqkv,
    const void* __restrict__ wo, const void* __restrict__ proj,
    const void* __restrict__ pi0, const void* __restrict__ pi1,
    const void* __restrict__ gam, const void* __restrict__ bet,
    int* __restrict__ flag, __bf16* __restrict__ hb, __bf16* __restrict__ wt,
    __bf16* __restrict__ wot, __bf16* __restrict__ projT,
    __bf16* __restrict__ pi0b, __bf16* __restrict__ pi1b,
    __bf16* __restrict__ gamb, __bf16* __restrict__ betb,
    __bf16* __restrict__ projB, __bf16* __restrict__ wotB) {
  __shared__ float T[64][69];
  __shared__ int redw[4];
  const int tid = threadIdx.x;
  int cnt = 0;
  {
    const unsigned short* hbits = (const unsigned short*)h;
    for (int i = 0; i < 16; ++i) {
      const unsigned short u = hbits[tid * 16 + i];
      if (((u >> 7) & 0xFF) >= 0xA0) ++cnt;
    }
  }
#pragma unroll
  for (int msk = 1; msk < 64; msk <<= 1) cnt += __shfl_xor(cnt, msk);
  if ((tid & 63) == 0) redw[tid >> 6] = cnt;
  __syncthreads();
  const int f32 = (redw[0] + redw[1] + redw[2] + redw[3] >= 64) ? 1 : 0;

  const int blk = blockIdx.x;
  if (blk < PREP_HB) {
    const int i = blk * 256 + tid;
    if (f32) {
      const f32x4* s = (const f32x4*)h;
      const f32x4 a = s[i * 2], b = s[i * 2 + 1];
      bf16x8 t;
      t[0] = (__bf16)a[0]; t[1] = (__bf16)a[1]; t[2] = (__bf16)a[2]; t[3] = (__bf16)a[3];
      t[4] = (__bf16)b[0]; t[5] = (__bf16)b[1]; t[6] = (__bf16)b[2]; t[7] = (__bf16)b[3];
      *reinterpret_cast<bf16x8*>(hb + (long)i * 8) = t;
    } else {
      *reinterpret_cast<bf16x8*>(hb + (long)i * 8) = ((const bf16x8*)h)[i];
    }
    return;
  }
  const void* src; __bf16* dst; int M, N, n0, m0;
  int pjx = -1, wox = -1;
  if (blk < PREP_HB + PREP_WT) {
    const int x = blk - PREP_HB;
    src = wqkv; dst = wt; M = 512; N = 2048; n0 = (x & 31) * 64; m0 = (x >> 5) * 64;
  } else if (blk < PREP_HB + PREP_WT + PREP_WOT) {
    const int x = blk - PREP_HB - PREP_WT;
    src = wo; dst = wot; M = 512; N = 512; n0 = (x & 7) * 64; m0 = (x >> 3) * 64;
    wox = x;
  } else if (blk < PREP_HB + PREP_WT + PREP_WOT + PREP_PJ) {
    const int x = blk - PREP_HB - PREP_WT - PREP_WOT;
    src = proj; dst = projT; M = 64; N = 256; n0 = x * 64; m0 = 0;
    pjx = x;
  } else {
    if (tid == 0) flag[0] = f32;
    if (f32) {
      const float* s0 = (const float*)pi0; const float* s1 = (const float*)pi1;
      const float* s2 = (const float*)gam; const float* s3 = (const float*)bet;
      for (int i = tid; i < NH * 256; i += 256) { pi0b[i] = (__bf16)s0[i]; pi1b[i] = (__bf16)s1[i]; }
      for (int i = tid; i < DM; i += 256)      { gamb[i] = (__bf16)s2[i]; betb[i] = (__bf16)s3[i]; }
    } else {
      const __bf16* s0 = (const __bf16*)pi0; const __bf16* s1 = (const __bf16*)pi1;
      const __bf16* s2 = (const __bf16*)gam; const __bf16* s3 = (const __bf16*)bet;
      for (int i = tid; i < NH * 256; i += 256) { pi0b[i] = s0[i]; pi1b[i] = s1[i]; }
      for (int i = tid; i < DM; i += 256)      { gamb[i] = s2[i]; betb[i] = s3[i]; }
    }
    return;
  }
  if (f32) {
    const float* s = (const float*)src;
#pragma unroll
    for (int rep = 0; rep < 16; ++rep) {
      const int i = rep * 4 + (tid >> 6), j = tid & 63;
      T[i][j] = s[(long)(m0 + i) * N + n0 + j];
    }
  } else {
    const __bf16* s = (const __bf16*)src;
#pragma unroll
    for (int rep = 0; rep < 16; ++rep) {
      const int i = rep * 4 + (tid >> 6), j = tid & 63;
      T[i][j] = (float)s[(long)(m0 + i) * N + n0 + j];
    }
  }
  __syncthreads();
#pragma unroll
  for (int rep = 0; rep < 16; ++rep) {
    const int i = rep * 4 + (tid >> 6), j = tid & 63;
    dst[(long)(n0 + i) * M + m0 + j] = (__bf16)T[j][i];
  }
  if (pjx >= 0) {
    // fragment-native pack. T[d][p-n0] (rows = d, cols = feature):
    const int lane = tid & 63, sub = tid >> 6;
    const int mm = lane & 15, qq = lane >> 4;
#pragma unroll
    for (int kk2 = 0; kk2 < 2; ++kk2) {
      bf16x8 v;
#pragma unroll
      for (int e = 0; e < 8; ++e) v[e] = (__bf16)T[kk2 * 32 + qq * 8 + e][sub * 16 + mm];
      *reinterpret_cast<bf16x8*>(projB + ((pjx * 4 + sub) * 2 + kk2) * 512 + lane * 8) = v;
    }
  }
  if (wox >= 0) {
    // wotB pack: chunk (cb0+sub, kk0+kk2), elem e = wo[k][n] = T[..][..].
    const int lane = tid & 63, sub = tid >> 6;
    const int mm = lane & 15, qq = lane >> 4;
    const int cb0 = n0 >> 4, kk0 = m0 >> 5;
#pragma unroll
    for (int kk2 = 0; kk2 < 2; ++kk2) {
      bf16x8 v;
#pragma unroll
      for (int e = 0; e < 8; ++e) v[e] = (__bf16)T[kk2 * 32 + qq * 8 + e][sub * 16 + mm];
      *reinterpret_cast<bf16x8*>(wotB + (((cb0 + sub) * 16) + kk0 + kk2) * 512 + lane * 8) = v;
    }
  }
}

// ---------------------------------------------------------------------------
// K1: qkv = hb @ w_qkv, 128x128 tile, BK=64, per-wave 64x64 (validated r13).
// ---------------------------------------------------------------------------
__global__ __launch_bounds__(256) void gemm_h_wqkv(const __bf16* __restrict__ A,
                                                   const __bf16* __restrict__ Bt,
                                                   __bf16* __restrict__ C) {
  __shared__ __bf16 At[128][72];
  __shared__ __bf16 Bts[128][72];
  const int n0 = blockIdx.x * 128, m0 = blockIdx.y * 128;
  const int tid = threadIdx.x, lane = tid & 63, wv = tid >> 6;
  const int m = lane & 15, q = lane >> 4;
  const int wr = (wv >> 1) * 64, wc = (wv & 1) * 64;
  const int r = tid >> 1, c0 = (tid & 1) * 32;
  const __bf16* ap = A + (long)(m0 + r) * DM + c0;
  const __bf16* bp = Bt + (long)(n0 + r) * DM + c0;
  f32x4 acc[4][4];
#pragma unroll
  for (int i = 0; i < 4; ++i)
#pragma unroll
    for (int j = 0; j < 4; ++j) acc[i][j] = f32x4{0.f, 0.f, 0.f, 0.f};

  bf16x8 ar[4], br[4];
#pragma unroll
  for (int j = 0; j < 4; ++j) {
    ar[j] = *reinterpret_cast<const bf16x8*>(ap + j * 8);
    br[j] = *reinterpret_cast<const bf16x8*>(bp + j * 8);
  }
  for (int k0 = 0; k0 < DM; k0 += 64) {
    __syncthreads();
#pragma unroll
    for (int j = 0; j < 4; ++j) {
      *reinterpret_cast<bf16x8*>(&At[r][c0 + j * 8]) = ar[j];
      *reinterpret_cast<bf16x8*>(&Bts[r][c0 + j * 8]) = br[j];
    }
    if (k0 + 64 < DM) {
#pragma unroll
      for (int j = 0; j < 4; ++j) {
        ar[j] = *reinterpret_cast<const bf16x8*>(ap + k0 + 64 + j * 8);
        br[j] = *reinterpret_cast<const bf16x8*>(bp + k0 + 64 + j * 8);
      }
    }
    __syncthreads();
#pragma unroll
    for (int kk = 0; kk < 2; ++kk) {
      bf16x8 af[4], bfv[4];
#pragma unroll
      for (int i = 0; i < 4; ++i) {
        af[i]  = *reinterpret_cast<const bf16x8*>(&At[wr + i * 16 + m][kk * 32 + q * 8]);
        bfv[i] = *reinterpret_cast<const bf16x8*>(&Bts[wc + i * 16 + m][kk * 32 + q * 8]);
      }
#pragma unroll
      for (int ai = 0; ai < 4; ++ai)
#pragma unroll
        for (int bi = 0; bi < 4; ++bi)
          acc[ai][bi] = MFMA16(af[ai], bfv[bi], acc[ai][bi]);
    }
  }
#pragma unroll
  for (int ai = 0; ai < 4; ++ai)
#pragma unroll
    for (int r2 = 0; r2 < 4; ++r2)
#pragma unroll
      for (int bi = 0; bi < 4; ++bi)
        C[(long)(m0 + wr + ai * 16 + q * 4 + r2) * QKVN + n0 + wc + bi * 16 + m] =
            (__bf16)acc[ai][bi][r2];
}

// ---------------------------------------------------------------------------
// K2: kf-features + FUSED V-pack (validated round 15).
// ---------------------------------------------------------------------------
__global__ __launch_bounds__(256) void features_mfma(const __bf16* __restrict__ qkv,
                                                     const __bf16* __restrict__ projB,
                                                     const __bf16* __restrict__ pi0,
                                                     const __bf16* __restrict__ pi1,
                                                     __bf16* __restrict__ kf,
                                                     __bf16* __restrict__ vt) {
  const int st = blockIdx.x;
  const int l0 = st * 64;
  const int bh = blockIdx.y;
  const int h = bh & 7, b = bh >> 3;
  const int tid = threadIdx.x, lane = tid & 63, wv = tid >> 6;
  const int m = lane & 15, q = lane >> 4;
  __shared__ __bf16 As[2][64][72];   // k1 / k2 tiles: 64 l-rows x 64 d
  __shared__ __bf16 VT[64][72];      // V transpose [d][s]

  {
    const int r = tid >> 2, c0 = (tid & 3) * 16;
    const __bf16* ap = qkv + (long)((l0 + r) * B_SZ + b) * QKVN + h * 256 + 64 + c0;
#pragma unroll
    for (int t2 = 0; t2 < 2; ++t2) {
      *reinterpret_cast<bf16x8*>(&As[t2][r][c0]) =
          *reinterpret_cast<const bf16x8*>(ap + t2 * 64);
      *reinterpret_cast<bf16x8*>(&As[t2][r][c0 + 8]) =
          *reinterpret_cast<const bf16x8*>(ap + t2 * 64 + 8);
    }
    // V slice -> transpose into VT
    const __bf16* vp = ap + 128;       // offset 192 = 64 + 128
#pragma unroll
    for (int j = 0; j < 16; ++j) VT[c0 + j][r] = vp[j];
  }
  const int l = l0 + wv * 16 + m;          // this thread's sequence row
  const float p0w = (float)pi0[h * 256 + l];
  const float p1w = (float)pi1[h * 256 + l];
  const float SQ = 0.35355339f;            // 64^-0.25
  const float SK2 = 0.24748737f;           // 0.7 * 64^-0.25
  __syncthreads();

  // V-pack store (fragment-native chunks), overlaps following VALU work
  {
    const int c2 = tid >> 6;
    const int d = c2 * 16 + m;
#pragma unroll
    for (int kk = 0; kk < 2; ++kk) {
      const bf16x8 v = *reinterpret_cast<const bf16x8*>(&VT[d][kk * 32 + q * 8]);
      *reinterpret_cast<bf16x8*>(vt + (((long)bh * 8 + st * 2 + kk) * 4 + c2) * 512 + lane * 8) = v;
    }
  }

  f32x4 acc1[16], acc2[16];
#pragma unroll
  for (int c = 0; c < 16; ++c) {
    acc1[c] = f32x4{0.f, 0.f, 0.f, 0.f};
    acc2[c] = f32x4{0.f, 0.f, 0.f, 0.f};
  }
#pragma unroll
  for (int kk = 0; kk < 2; ++kk) {
    const bf16x8 x1 = *reinterpret_cast<const bf16x8*>(&As[0][wv * 16 + m][kk * 32 + q * 8]);
    const bf16x8 x2 = *reinterpret_cast<const bf16x8*>(&As[1][wv * 16 + m][kk * 32 + q * 8]);
#pragma unroll
    for (int c = 0; c < 16; ++c) {
      const bf16x8 wf =
          *reinterpret_cast<const bf16x8*>(projB + (c * 2 + kk) * 512 + lane * 8);
      acc1[c] = MFMA16(wf, x1, acc1[c]);   // acc[c][r] = [l=wv*16+m][p=c*16+q*4+r]
      acc2[c] = MFMA16(wf, x2, acc2[c]);
    }
  }
  float mx1 = 0.f, mx2 = 0.f;
#pragma unroll
  for (int c = 0; c < 16; ++c)
#pragma unroll
    for (int r = 0; r < 4; ++r) {
      mx1 = fmaxf(mx1, fabsf(acc1[c][r] * SQ));
      mx2 = fmaxf(mx2, fabsf(acc2[c][r] * SK2));
    }
  mx1 = fmaxf(mx1, __shfl_xor(mx1, 16)); mx1 = fmaxf(mx1, __shfl_xor(mx1, 32));
  mx2 = fmaxf(mx2, __shfl_xor(mx2, 16)); mx2 = fmaxf(mx2, __shfl_xor(mx2, 32));
  const float C21 = __expf(-2.f * mx1);
  const float C22 = __expf(-2.f * mx2);
  float sm1 = 0.f, sm2 = 0.f;
#pragma unroll
  for (int c = 0; c < 16; ++c)
#pragma unroll
    for (int r = 0; r < 4; ++r) {
      const float e11 = __expf(acc1[c][r] * SQ - mx1);
      const float e12 = __expf(acc2[c][r] * SK2 - mx2);
      sm1 += e11 + C21 * __builtin_amdgcn_rcpf(e11);
      sm2 += e12 + C22 * __builtin_amdgcn_rcpf(e12);
      acc1[c][r] = e11;
      acc2[c][r] = e12;
    }
  sm1 += __shfl_xor(sm1, 16); sm1 += __shfl_xor(sm1, 32);
  sm2 += __shfl_xor(sm2, 16); sm2 += __shfl_xor(sm2, 32);
  const float w1 = p0w * __builtin_amdgcn_rcpf(sm1);
  const float w2 = p1w * __builtin_amdgcn_rcpf(sm2);
  const float K1 = C21 * w1, K2 = C22 * w2;
  // fragment-native store: chunk [lt = l>>4][c], lane offset = lane*8
  __bf16* op = kf + (((long)bh * 16 + (l >> 4)) * 16) * 512 + lane * 8;
#pragma unroll
  for (int c = 0; c < 16; ++c) {
    bf16x8 v;
#pragma unroll
    for (int r = 0; r < 4; ++r) {
      v[r]     = (__bf16)(w1 * acc1[c][r] + w2 * acc2[c][r]);
      v[4 + r] = (__bf16)(K1 * __builtin_amdgcn_rcpf(acc1[c][r]) +
                          K2 * __builtin_amdgcn_rcpf(acc2[c][r]));
    }
    *reinterpret_cast<bf16x8*>(op + c * 512) = v;
  }
}

// ---------------------------------------------------------------------------
// K3: flash (validated round 18): kf step-tile staged into LDS via
// global_load_lds (contiguous 64KB in lane order), 2 barriers/step,
// longest-first dispatch, XCD locality.
// ---------------------------------------------------------------------------
__global__ __launch_bounds__(256, 2) void flash_mfma(const __bf16* __restrict__ qkv,
                                                     const __bf16* __restrict__ projB,
                                                     const __bf16* __restrict__ kf,
                                                     const __bf16* __restrict__ vt,
                                                     __bf16* __restrict__ att) {
  const int id = blockIdx.x;
  const int bh = id & 255;
  const int t  = 3 - (id >> 8);          // longest-first dispatch order
  const int h = bh & 7, b = bh >> 3;
  const int tid = threadIdx.x, lane = tid & 63, wv = tid >> 6;
  const int m = lane & 15, q = lane >> 4;
  __shared__ __bf16 Kst[4 * 16 * 512];   // 64 KB staged kf step-tile
  __shared__ __bf16 Pt[64][72];          // wave-private rows

  // ---------------- feature phase: qT[16] in-register ----------------
  const float SQ = 0.35355339f;          // 64^-0.25
  f32x4 acc[16];
#pragma unroll
  for (int c = 0; c < 16; ++c) acc[c] = f32x4{0.f, 0.f, 0.f, 0.f};
  const __bf16* xb = qkv + (long)((t * 64 + wv * 16 + m) * B_SZ + b) * QKVN + h * 256;
#pragma unroll
  for (int kk = 0; kk < 2; ++kk) {
    const bf16x8 xf = *reinterpret_cast<const bf16x8*>(xb + kk * 32 + q * 8);
#pragma unroll
    for (int c = 0; c < 16; ++c) {
      const bf16x8 wf =
          *reinterpret_cast<const bf16x8*>(projB + (c * 2 + kk) * 512 + lane * 8);
      acc[c] = MFMA16(wf, xf, acc[c]);   // acc[c][r] = qf-pre[l=wv*16+m][p=c*16+q*4+r]
    }
  }
  float mx = 0.f;
#pragma unroll
  for (int c = 0; c < 16; ++c)
#pragma unroll
    for (int r = 0; r < 4; ++r) mx = fmaxf(mx, fabsf(acc[c][r] * SQ));
  mx = fmaxf(mx, __shfl_xor(mx, 16));
  mx = fmaxf(mx, __shfl_xor(mx, 32));
  const float C2 = __expf(-2.f * mx);
  float sm = 0.f;
#pragma unroll
  for (int c = 0; c < 16; ++c)
#pragma unroll
    for (int r = 0; r < 4; ++r) {
      const float e1 = __expf(acc[c][r] * SQ - mx);
      sm += e1 + C2 * __builtin_amdgcn_rcpf(e1);
      acc[c][r] = e1;
    }
  sm += __shfl_xor(sm, 16);
  sm += __shfl_xor(sm, 32);
  const float inv = __builtin_amdgcn_rcpf(sm);
  const float K2 = C2 * inv;
  bf16x8 qT[16];                         // A-frags, k = q*8 + (r + 4*neg)
#pragma unroll
  for (int c = 0; c < 16; ++c) {
    bf16x8 v;
#pragma unroll
    for (int r = 0; r < 4; ++r) {
      v[r]     = (__bf16)(acc[c][r] * inv);
      v[4 + r] = (__bf16)(K2 * __builtin_amdgcn_rcpf(acc[c][r]));
    }
    qT[c] = v;
  }

  // ---------------- main loop: LDS-staged kf, 2 barriers/step ----------------
  f32x4 o[4];
#pragma unroll
  for (int i = 0; i < 4; ++i) o[i] = f32x4{0.f, 0.f, 0.f, 0.f};
  float den[4] = {0.f, 0.f, 0.f, 0.f};

  const __bf16* kf_bh = kf + (long)bh * (16 * 16 * 512);
  const __bf16* vtb = vt + (long)bh * (8 * 4 * 512) + lane * 8;

  for (int st = 0; st <= t; ++st) {
    __syncthreads();                     // previous step's reads done
    {
      const __bf16* gsrc =
          kf_bh + ((long)(st * 4) * 16 + wv * 16) * 512 + lane * 8;
      __bf16* ldst = Kst + (wv * 16) * 512;
#pragma unroll
      for (int j = 0; j < 16; ++j)
        gload_lds16(gsrc + j * 512, ldst + j * 512);
    }
    // V fragments for this step (register-direct, L1-shared across waves)
    bf16x8 vf[8];
#pragma unroll
    for (int kk = 0; kk < 2; ++kk)
#pragma unroll
      for (int c = 0; c < 4; ++c)
        vf[kk * 4 + c] =
            *reinterpret_cast<const bf16x8*>(vtb + (((long)st * 2 + kk) * 4 + c) * 512);
    __syncthreads();                     // staging visible (vmcnt drained)

    f32x4 s[4];
#pragma unroll
    for (int i = 0; i < 4; ++i) s[i] = f32x4{0.f, 0.f, 0.f, 0.f};
#pragma unroll
    for (int g = 0; g < 16; ++g) {
      const __bf16* kp = Kst + (long)g * 512 + lane * 8;
      const bf16x8 kb0 = *reinterpret_cast<const bf16x8*>(kp);
      const bf16x8 kb1 = *reinterpret_cast<const bf16x8*>(kp + 16 * 512);
      const bf16x8 kb2 = *reinterpret_cast<const bf16x8*>(kp + 32 * 512);
      const bf16x8 kb3 = *reinterpret_cast<const bf16x8*>(kp + 48 * 512);
      s[0] = MFMA16(qT[g], kb0, s[0]);
      s[1] = MFMA16(qT[g], kb1, s[1]);
      s[2] = MFMA16(qT[g], kb2, s[2]);
      s[3] = MFMA16(qT[g], kb3, s[3]);
    }
    const bool last = (st == t);
#pragma unroll
    for (int c = 0; c < 4; ++c)
#pragma unroll
      for (int r = 0; r < 4; ++r) {
        const int row = wv * 16 + q * 4 + r, col = c * 16 + m;
        const float v = (last && col > row) ? 0.f : s[c][r];
        den[r] += v;
        Pt[row][col] = (__bf16)v;
      }
#pragma unroll
    for (int kk = 0; kk < 2; ++kk) {
      const bf16x8 pf = *reinterpret_cast<const bf16x8*>(&Pt[wv * 16 + m][kk * 32 + q * 8]);
#pragma unroll
      for (int c = 0; c < 4; ++c)
        o[c] = MFMA16(pf, vf[kk * 4 + c], o[c]);
    }
  }
#pragma unroll
  for (int r = 0; r < 4; ++r) {
    float d = den[r];
    d += __shfl_xor(d, 1); d += __shfl_xor(d, 2);
    d += __shfl_xor(d, 4); d += __shfl_xor(d, 8);
    const float invd = 0.125f / (d + 1e-5f);           // SCALE=64^-0.5, EPS
    const int row = t * 64 + wv * 16 + q * 4 + r;
#pragma unroll
    for (int c = 0; c < 4; ++c)
      att[((long)(row * B_SZ + b)) * DM + h * DH + c * 16 + m] = (__bf16)(o[c][r] * invd);
  }
}

// ---------------------------------------------------------------------------
// K4+K5 FUSED, round 20: 512 blocks x 256 threads (16 rows/block, 4 waves
// each owning a 128-col range) -> 2 blocks/CU so stage/epilogue of one block
// hides under compute of the other (round-11's grid=256x512 was 1 block/CU).
// Same wotB fragment path, same LN epilogue, same numerics.
// ---------------------------------------------------------------------------
__global__ __launch_bounds__(256) void gemm_wo_ln(const __bf16* __restrict__ att,
                                                  const __bf16* __restrict__ wotB,
                                                  const __bf16* __restrict__ hb,
                                                  const __bf16* __restrict__ gamma,
                                                  const __bf16* __restrict__ beta,
                                                  const int* __restrict__ flag,
                                                  void* __restrict__ out) {
  const int f32 = flag[0];
  const int bm = blockIdx.x;             // rows [bm*16, bm*16+16)
  const int tid = threadIdx.x, lane = tid & 63, wv = tid >> 6;
  const int m = lane & 15, q = lane >> 4;
  const int wc = wv * 128;               // col range per wave
  __shared__ __bf16 As[16][520];
  __shared__ float RedS[16][4], RedS2[16][4];

  // stage att rows: 16 rows x 512 cols, fully coalesced bf16x8 chunks
#pragma unroll
  for (int j = 0; j < 4; ++j) {
    const int ci = j * 256 + tid;
    const int r = ci >> 6, c = (ci & 63) * 8;
    *reinterpret_cast<bf16x8*>(&As[r][c]) =
        *reinterpret_cast<const bf16x8*>(att + ((long)(bm * 16 + r)) * DM + c);
  }
  __syncthreads();

  f32x4 acc[8];
#pragma unroll
  for (int i = 0; i < 8; ++i) acc[i] = f32x4{0.f, 0.f, 0.f, 0.f};
#pragma unroll
  for (int kk = 0; kk < 16; ++kk) {
    const bf16x8 af = *reinterpret_cast<const bf16x8*>(&As[m][kk * 32 + q * 8]);
#pragma unroll
    for (int cbl = 0; cbl < 8; ++cbl) {
      const bf16x8 bf = *reinterpret_cast<const bf16x8*>(
          wotB + (((wv * 8 + cbl) * 16) + kk) * 512 + lane * 8);
      acc[cbl] = MFMA16(af, bf, acc[cbl]);
    }
  }

  // residual + per-row stats
  float s[4] = {0.f, 0.f, 0.f, 0.f}, s2[4] = {0.f, 0.f, 0.f, 0.f};
#pragma unroll
  for (int cbl = 0; cbl < 8; ++cbl)
#pragma unroll
    for (int r = 0; r < 4; ++r) {
      const long row = (long)bm * 16 + q * 4 + r;
      const int col = wc + cbl * 16 + m;
      const float x = acc[cbl][r] + (float)hb[row * DM + col];
      acc[cbl][r] = x;
      s[r] += x;
      s2[r] += x * x;
    }
#pragma unroll
  for (int msk = 1; msk < 16; msk <<= 1)
#pragma unroll
    for (int r = 0; r < 4; ++r) {
      s[r] += __shfl_xor(s[r], msk);
      s2[r] += __shfl_xor(s2[r], msk);
    }
  if (m == 0) {
#pragma unroll
    for (int r = 0; r < 4; ++r) {
      RedS[q * 4 + r][wv] = s[r];
      RedS2[q * 4 + r][wv] = s2[r];
    }
  }
  __syncthreads();

  float gam[8], bet[8];
#pragma unroll
  for (int cbl = 0; cbl < 8; ++cbl) {
    gam[cbl] = (float)gamma[wc + cbl * 16 + m];
    bet[cbl] = (float)beta[wc + cbl * 16 + m];
  }
#pragma unroll
  for (int r = 0; r < 4; ++r) {
    const int rl = q * 4 + r;
    const float fs = RedS[rl][0] + RedS[rl][1] + RedS[rl][2] + RedS[rl][3];
    const float fs2 = RedS2[rl][0] + RedS2[rl][1] + RedS2[rl][2] + RedS2[rl][3];
    const float mu = fs * (1.f / 512.f);
    const float var = fs2 * (1.f / 512.f) - mu * mu;
    const float rstd = rsqrtf(var + 1e-5f);
    const long row = (long)bm * 16 + rl;
#pragma unroll
    for (int cbl = 0; cbl < 8; ++cbl) {
      const int col = wc + cbl * 16 + m;
      stmix(out, row * DM + col, (acc[cbl][r] - mu) * rstd * gam[cbl] + bet[cbl], f32);
    }
  }
}

// ---------------------------------------------------------------------------
extern "C" void kernel_launch(void* const* d_in, const int* in_sizes, int n_in,
                              void* d_out, int out_size, void* d_ws, size_t ws_size,
                              hipStream_t stream) {
  (void)in_sizes; (void)n_in; (void)out_size; (void)ws_size;
  char* ws = (char*)d_ws;
  __bf16* qkv   = (__bf16*)ws;
  int*    flag  = (int*)(ws + 33554432);
  __bf16* wt    = (__bf16*)(ws + 33554688);
  __bf16* wot   = (__bf16*)(ws + 35651840);
  __bf16* att   = (__bf16*)(ws + 36176128);
  __bf16* vt    = (__bf16*)(ws + 44564736);
  __bf16* hb    = (__bf16*)(ws + 52953344);
  __bf16* projT = (__bf16*)(ws + 61341952);
  __bf16* pi0b  = (__bf16*)(ws + 61374720);
  __bf16* pi1b  = (__bf16*)(ws + 61378816);
  __bf16* gamb  = (__bf16*)(ws + 61382912);
  __bf16* betb  = (__bf16*)(ws + 61383936);
  __bf16* projB = (__bf16*)(ws + 78163968);  // 32 KB fragment-native proj
  __bf16* wotB  = (__bf16*)(ws + 78196736);  // 512 KB fragment-native w_o^T
  __bf16* kf    = (__bf16*)(ws + 128493824);

  prep<<<PREP_BLOCKS, 256, 0, stream>>>(d_in[0], d_in[1], d_in[2], d_in[7],
                                        d_in[5], d_in[6], d_in[3], d_in[4],
                                        flag, hb, wt, wot, projT,
                                        pi0b, pi1b, gamb, betb, projB, wotB);
  gemm_h_wqkv<<<dim3(16, 64), 256, 0, stream>>>(hb, wt, qkv);
  features_mfma<<<dim3(4, 256), 256, 0, stream>>>(qkv, projB, pi0b, pi1b, kf, vt);
  flash_mfma<<<dim3(1024), 256, 0, stream>>>(qkv, projB, kf, vt, att);
  gemm_wo_ln<<<dim3(512), 256, 0, stream>>>(att, wotB, gamb ? hb : hb, gamb, betb, flag, d_out);
}